// Round 13
// baseline (193.212 us; speedup 1.0000x reference)
//
#include <hip/hip_runtime.h>
#include <hip/hip_bf16.h>
#include <cstdint>
#include <cstddef>

// MHA B=2,S=2048,D=1024,H=16,HD=64.
// cvt(fp32->bf16) -> fused QKV GEMM (128x128 tiles, 4 waves/acc[4][4], 2-phase
// dbuf 64KB -> 2 blocks/CU co-residency, T2 LDS XOR-swizzle via pre-swizzled
// global source + XOR'd reads, XCD 2D swizzle; V pre-transposed) ->
// flash attn (r8 structure, unchanged) -> O GEMM (64x128, 2-phase, T2).
//
// r6: never feed two copies of one value to "+v","+v" permlane asm (CSE).
// r7: GEMM wave-count null. r8: 2-phase = -8.5us. r9: acc ratio null (but
// measured WITH bank conflicts). r10: prologue buf offset bug. r11: 256^2
// tile null (conflicts still present). r12: T2 swizzle = -8.2us (conflicts
// were real). r13 THEORY: qkv at 256^2 = 128KB LDS = 1 block/CU = zero
// co-residency (m114: resident peers cover barrier drain + LDS stalls).
// 128^2 + 2-phase + T2 + 2 blocks/CU is the untested combination.

#define B_  2
#define S_  2048
#define D_  1024
#define H_  16
#define HD_ 64

typedef __bf16 bf16x8 __attribute__((ext_vector_type(8)));
typedef __bf16 bf16x4 __attribute__((ext_vector_type(4)));
typedef float  f32x4  __attribute__((ext_vector_type(4)));

// ---- async global->LDS, 16B per lane. LDS dest must be wave-uniform base;
// HW adds lane*16 (guide §5 m97/m104). AS(3) ptr = low 32 bits of flat addr.
__device__ __forceinline__ void async16(const __bf16* g, const __bf16* l) {
  __builtin_amdgcn_global_load_lds(
      (const __attribute__((address_space(1))) void*)(uintptr_t)g,
      (__attribute__((address_space(3))) void*)(uint32_t)(uintptr_t)l,
      16, 0, 0);
}

// v_cvt_pk_bf16_f32: dst.lo16 = bf16(lo), dst.hi16 = bf16(hi)
__device__ __forceinline__ unsigned cvt_pk_bf16(float lo, float hi) {
  unsigned r;
  asm("v_cvt_pk_bf16_f32 %0, %1, %2" : "=v"(r) : "v"(lo), "v"(hi));
  return r;
}

// ---------------- fp32 -> bf16 convert (x + 4 weights) ----------------
__global__ __launch_bounds__(256) void cvt_all(const float* __restrict__ x,
    const float* __restrict__ wq, const float* __restrict__ wk,
    const float* __restrict__ wv, const float* __restrict__ wo,
    __bf16* __restrict__ xb, __bf16* __restrict__ wqb, __bf16* __restrict__ wkb,
    __bf16* __restrict__ wvb, __bf16* __restrict__ wob) {
  const int sel = blockIdx.y;
  const float* src; __bf16* dst; int n;
  if      (sel == 0) { src = x;  dst = xb;  n = B_ * S_ * D_; }
  else if (sel == 1) { src = wq; dst = wqb; n = D_ * D_; }
  else if (sel == 2) { src = wk; dst = wkb; n = D_ * D_; }
  else if (sel == 3) { src = wv; dst = wvb; n = D_ * D_; }
  else               { src = wo; dst = wob; n = D_ * D_; }
  for (int i = blockIdx.x * 256 + threadIdx.x; i * 4 < n; i += gridDim.x * 256) {
    const float4 v = *(const float4*)(src + (size_t)i * 4);
    bf16x4 o;
    o[0] = (__bf16)v.x; o[1] = (__bf16)v.y; o[2] = (__bf16)v.z; o[3] = (__bf16)v.w;
    *(bf16x4*)(dst + (size_t)i * 4) = o;
  }
}

// ---------------- fused QKV GEMM: 128x128, 2-phase, T2, 2 blocks/CU ---------
// Grid 24n x 32m = 768 blocks. 256 thr / 4 waves (2x2), acc[4][4] (m97 shape,
// MFMA:ds_read = 2.0). 2-phase dbuf (64KB LDS -> 2 blocks/CU): stage K-step
// t+1 into buf^1 before computing t; one barrier per K-step. T2 swizzle:
// global col chunk pre-XOR'd by row&7 (= lane>>3 here), reads XOR (l15&7).
// XCD swizzle (16m x 6n per XCD). LDS-aliased epilogue (cs = smem).
// sel 0/1 (Q,K): bf16x8 row-major stores. sel 2 (V): transposed -> Vt.
__global__ __launch_bounds__(256, 2) void qkv_gemm(const __bf16* __restrict__ xb,
                                                   const __bf16* __restrict__ wqkv,
                                                   __bf16* __restrict__ qkv) {
  __shared__ __align__(16) char smem[65536];   // 2 x (As 16K + Bs 16K)
  __bf16* cs = (__bf16*)smem;                  // 64*136*2B = 17408; post-loop

  const int lin = blockIdx.y * 24 + blockIdx.x;   // 0..767
  const int xcd = lin & 7, slot = lin >> 3;       // slot 0..95
  const int mi = xcd >> 2, ni = xcd & 3;
  const int mB = mi * 16 + slot / 6;              // 0..31
  const int nB = ni * 6  + slot % 6;              // 0..23
  const int m0  = mB * 128;
  const int sel = nB >> 3;                        // 0..2 -> Q,K,V
  const int n0s = (nB & 7) * 128;                 // col offset within sel
  const int n0w = nB * 128;                       // row offset in packed weights
  constexpr int K = D_, N = D_;
  constexpr size_t NTE = (size_t)B_ * S_ * D_;

  const int tid  = threadIdx.x, lane = tid & 63, wave = tid >> 6;  // 0..3
  const int l15  = lane & 15,   quad = lane >> 4;
  const int wr   = wave >> 1,   wc   = wave & 1;   // 2 x 2 wave grid
  const int rx   = (l15 & 7) << 3;                 // read-side XOR (elems)
  // staging: chunk i covers row = wave*32 + i*8 + (lane>>3); row&7 = lane>>3.
  // T2: lane's LDS slot (lane&7) must hold global chunk (lane&7)^(row&7).
  const int rowl = lane >> 3;
  const int colS = (((lane & 7) ^ rowl) * 8);      // constant per lane

  f32x4 acc[4][4] = {};

  // prologue: stage K-step 0 into buf 0 (wave-uniform LDS dest)
  {
    __bf16* As = (__bf16*)(smem);
    __bf16* Bs = (__bf16*)(smem + 16384);
#pragma unroll
    for (int i = 0; i < 4; ++i) {
      const int row = wave * 32 + i * 8 + rowl;
      async16(xb   + (size_t)(m0  + row) * K + colS, As + (wave * 4 + i) * 512);
      async16(wqkv + (size_t)(n0w + row) * K + colS, Bs + (wave * 4 + i) * 512);
    }
  }
  __syncthreads();

  for (int t = 0; t < K / 64; ++t) {
    const int cur = t & 1;
    if (t + 1 < K / 64) {
      const int k0 = (t + 1) * 64;
      __bf16* As = (__bf16*)(smem + (cur ^ 1) * 32768);
      __bf16* Bs = (__bf16*)(smem + (cur ^ 1) * 32768 + 16384);
#pragma unroll
      for (int i = 0; i < 4; ++i) {
        const int row = wave * 32 + i * 8 + rowl;
        async16(xb   + (size_t)(m0  + row) * K + k0 + colS, As + (wave * 4 + i) * 512);
        async16(wqkv + (size_t)(n0w + row) * K + k0 + colS, Bs + (wave * 4 + i) * 512);
      }
    }
    const __bf16* As = (const __bf16*)(smem + cur * 32768);
    const __bf16* Bs = (const __bf16*)(smem + cur * 32768 + 16384);
#pragma unroll
    for (int kk = 0; kk < 2; ++kk) {
      bf16x8 af[4], bfv[4];
#pragma unroll
      for (int rt = 0; rt < 4; ++rt)
        af[rt] = *(const bf16x8*)(As + (wr * 64 + rt * 16 + l15) * 64 + ((kk * 32 + quad * 8) ^ rx));
#pragma unroll
      for (int ct = 0; ct < 4; ++ct)
        bfv[ct] = *(const bf16x8*)(Bs + (wc * 64 + ct * 16 + l15) * 64 + ((kk * 32 + quad * 8) ^ rx));
#pragma unroll
      for (int rt = 0; rt < 4; ++rt)
#pragma unroll
        for (int ct = 0; ct < 4; ++ct)
          acc[rt][ct] = __builtin_amdgcn_mfma_f32_16x16x32_bf16(af[rt], bfv[ct], acc[rt][ct], 0, 0, 0);
    }
    __syncthreads();  // drains staged loads (after compute) + guards buf reuse
  }

  // epilogue: two 64-row passes through cs[64][136]
  const int b  = m0 >> 11;       // batch (S_=2048 rows per batch)
  const int s0 = m0 & (S_ - 1);
  __bf16* vtb = qkv + 2 * NTE;   // Vt lives in the V slot
#pragma unroll
  for (int pass = 0; pass < 2; ++pass) {
    __syncthreads();  // prior pass's readers (or main loop) done
    if (wr == pass) {  // waves 0,1 own rows 0-63; waves 2,3 rows 64-127
#pragma unroll
      for (int rt = 0; rt < 4; ++rt)
#pragma unroll
        for (int ct = 0; ct < 4; ++ct)
#pragma unroll
          for (int r = 0; r < 4; ++r)
            cs[(rt * 16 + quad * 4 + r) * 136 + wc * 64 + ct * 16 + l15] =
                (__bf16)acc[rt][ct][r];
    }
    __syncthreads();
    if (sel < 2) {
      __bf16* C = qkv + (size_t)sel * NTE;
      const int cc = tid & 15, rr = tid >> 4;
#pragma unroll
      for (int p2 = 0; p2 < 4; ++p2) {
        const int row = p2 * 16 + rr;
        const bf16x8 v = *(const bf16x8*)(cs + row * 136 + cc * 8);
        *(bf16x8*)(C + (size_t)(m0 + pass * 64 + row) * N + n0s + cc * 8) = v;
      }
    } else {
      // transposed: output row = b*1024 + (n0s + e_loc), cols = s
      const int e_loc = tid >> 1, sh = (tid & 1) * 32;
      __bf16* dst = vtb + (size_t)(b * 1024 + n0s + e_loc) * S_ + s0 + pass * 64 + sh;
#pragma unroll
      for (int p2 = 0; p2 < 4; ++p2) {
        bf16x8 v;
#pragma unroll
        for (int j = 0; j < 8; ++j)
          v[j] = cs[(sh + p2 * 8 + j) * 136 + e_loc];
        *(bf16x8*)(dst + p2 * 8) = v;
      }
    }
  }
}

// ---------------- O GEMM: 64x128 tiles, 2-phase, T2-swizzled LDS ------------
// 256 thr / 4 waves (2x2), acc[2][4]. LDS 48KB dbuf. XCD 2D swizzle.
__global__ __launch_bounds__(256) void o_gemm(const __bf16* __restrict__ cb,
                                              const __bf16* __restrict__ wo,
                                              float* __restrict__ out) {
  __shared__ __align__(16) char smem[49152];   // 2 x (As 8K + Bs 16K)
  const int lin = blockIdx.y * 8 + blockIdx.x;   // 0..511
  const int xcd = lin & 7, slot = lin >> 3;      // slot 0..63
  const int mi = xcd >> 1, ni = xcd & 1;
  const int mB = mi * 16 + (slot >> 2);          // 0..63
  const int nB = ni * 4  + (slot & 3);           // 0..7
  const int m0 = mB * 64, n0 = nB * 128;
  constexpr int K = D_, N = D_;
  const int tid  = threadIdx.x, lane = tid & 63, wave = tid >> 6;  // 0..3
  const int l15  = lane & 15,   quad = lane >> 4;
  const int wr   = wave >> 1,   wc   = wave & 1;
  const int row8 = tid >> 3;
  const int colS = (((tid & 7) ^ (row8 & 7)) * 8);  // T2 swizzled global col
  const int rx   = (l15 & 7) << 3;                  // read-side XOR

  f32x4 acc[2][4] = {};
  {
    __bf16* As = (__bf16*)(smem);
    __bf16* Bs = (__bf16*)(smem + 8192);
#pragma unroll
    for (int i = 0; i < 2; ++i)
      async16(cb + (size_t)(m0 + i * 32 + row8) * K + colS, As + i * 2048 + wave * 512);
#pragma unroll
    for (int i = 0; i < 4; ++i)
      async16(wo + (size_t)(n0 + i * 32 + row8) * K + colS, Bs + i * 2048 + wave * 512);
  }
  __syncthreads();

  for (int t = 0; t < K / 64; ++t) {
    const int cur = t & 1;
    if (t + 1 < K / 64) {
      const int k0 = (t + 1) * 64;
      __bf16* As = (__bf16*)(smem + (cur ^ 1) * 24576);
      __bf16* Bs = (__bf16*)(smem + (cur ^ 1) * 24576 + 8192);
#pragma unroll
      for (int i = 0; i < 2; ++i)
        async16(cb + (size_t)(m0 + i * 32 + row8) * K + k0 + colS, As + i * 2048 + wave * 512);
#pragma unroll
      for (int i = 0; i < 4; ++i)
        async16(wo + (size_t)(n0 + i * 32 + row8) * K + k0 + colS, Bs + i * 2048 + wave * 512);
    }
    const __bf16* As = (const __bf16*)(smem + cur * 24576);
    const __bf16* Bs = (const __bf16*)(smem + cur * 24576 + 8192);
#pragma unroll
    for (int kk = 0; kk < 2; ++kk) {
      bf16x8 af[2], bfv[4];
#pragma unroll
      for (int rt = 0; rt < 2; ++rt)
        af[rt] = *(const bf16x8*)(As + (wr * 32 + rt * 16 + l15) * 64 + ((kk * 32 + quad * 8) ^ rx));
#pragma unroll
      for (int ct = 0; ct < 4; ++ct)
        bfv[ct] = *(const bf16x8*)(Bs + (wc * 64 + ct * 16 + l15) * 64 + ((kk * 32 + quad * 8) ^ rx));
#pragma unroll
      for (int rt = 0; rt < 2; ++rt)
#pragma unroll
        for (int ct = 0; ct < 4; ++ct)
          acc[rt][ct] = __builtin_amdgcn_mfma_f32_16x16x32_bf16(af[rt], bfv[ct], acc[rt][ct], 0, 0, 0);
    }
    __syncthreads();
  }
#pragma unroll
  for (int rt = 0; rt < 2; ++rt)
#pragma unroll
    for (int ct = 0; ct < 4; ++ct)
#pragma unroll
      for (int r = 0; r < 4; ++r) {
        const int row = m0 + wr * 32 + rt * 16 + quad * 4 + r;
        const int col = n0 + wc * 64 + ct * 16 + l15;
        out[(size_t)row * N + col] = acc[rt][ct][r];
      }
}

// ---------------- flash attention: single barrier per KV tile (r8) ----------
// 8 waves x 16 q, 128-key tiles. S^T = K·Q^T: lane holds P[q=l15][32 keys];
// in-register P via cvt_pk + permlane32/16_swap; row-sum l via ones-MFMA;
// max-reduce via __shfl_xor; defer-max (THR=8, exp2 domain); T14 reg-prefetch
// + dbuf K/V, single barrier/tile. No XCD swizzle (r5: L2-fit, m160).
// kt/vt padded (144/272 B strides) -> bank-conflict-benign.
__global__ __launch_bounds__(512, 4) void attn2(const __bf16* __restrict__ Q,
                                                const __bf16* __restrict__ K,
                                                const __bf16* __restrict__ Vt,
                                                const float* __restrict__ mask,
                                                __bf16* __restrict__ O) {
  constexpr int LKT = 72, LVT = 136;
  __shared__ __align__(16) __bf16 kt[2][128 * LKT];   // 2 x 18432 B
  __shared__ __align__(16) __bf16 vt[2][64 * LVT];    // 2 x 17408 B
  __shared__ __align__(16) float  mfull[S_];          // 8192 B (pre-scaled by log2e)

  const int tid  = threadIdx.x, lane = tid & 63, wave = tid >> 6;
  const int l15  = lane & 15,   quad = lane >> 4;
  const int b = blockIdx.z, h = blockIdx.y, q0 = blockIdx.x * 128;
  const size_t base   = (size_t)b * S_ * D_ + h * HD_;
  const size_t vtbase = (size_t)(b * H_ + h) * HD_ * S_;
  const int qw = q0 + wave * 16;
  constexpr float LOG2E = 1.44269504088896340736f;
  constexpr float SC    = 0.125f * LOG2E;          // 1/sqrt(HD) * log2(e)
  constexpr int  NT     = S_ / 128;

  // per-thread staging slots (2 x 16B each for K and V tiles)
  const int idx0 = tid,        kr0 = idx0 >> 3, kc0 = (idx0 & 7) * 8;
  const int idx1 = 512 + tid,  kr1 = idx1 >> 3, kc1 = (idx1 & 7) * 8;
  const int vr0 = idx0 >> 4, vc0 = (idx0 & 15) * 8;
  const int vr1 = idx1 >> 4, vc1 = (idx1 & 15) * 8;

  // Q fragments (B-operand: n=l15 -> q row, k = kb*32+quad*8+j)
  bf16x8 qf[2];
#pragma unroll
  for (int kb = 0; kb < 2; ++kb)
    qf[kb] = *(const bf16x8*)(Q + base + (size_t)(qw + l15) * D_ + kb * 32 + quad * 8);

  bf16x8 ones;
#pragma unroll
  for (int j = 0; j < 8; ++j) ones[j] = (__bf16)1.0f;

  float m_run = -1e30f;
  f32x4 oacc[4] = {};
  f32x4 lacc   = {};

  // prologue: mask table + tile 0 -> buf 0 + issue tile 1 loads
  bf16x8 rk0, rk1, rv0, rv1;
  rk0 = *(const bf16x8*)(K + base + (size_t)kr0 * D_ + kc0);
  rk1 = *(const bf16x8*)(K + base + (size_t)kr1 * D_ + kc1);
  rv0 = *(const bf16x8*)(Vt + vtbase + (size_t)vr0 * S_ + vc0);
  rv1 = *(const bf16x8*)(Vt + vtbase + (size_t)vr1 * S_ + vc1);
#pragma unroll
  for (int i = 0; i < S_ / 512; ++i)
    mfull[i * 512 + tid] = mask[(size_t)b * S_ + i * 512 + tid] * LOG2E;
  *(bf16x8*)(&kt[0][kr0 * LKT + kc0]) = rk0;
  *(bf16x8*)(&kt[0][kr1 * LKT + kc1]) = rk1;
  *(bf16x8*)(&vt[0][vr0 * LVT + vc0]) = rv0;
  *(bf16x8*)(&vt[0][vr1 * LVT + vc1]) = rv1;
  if (NT > 1) {  // issue tile 1 loads (land before their ds_write in iter 0)
    rk0 = *(const bf16x8*)(K + base + (size_t)(128 + kr0) * D_ + kc0);
    rk1 = *(const bf16x8*)(K + base + (size_t)(128 + kr1) * D_ + kc1);
    rv0 = *(const bf16x8*)(Vt + vtbase + (size_t)vr0 * S_ + 128 + vc0);
    rv1 = *(const bf16x8*)(Vt + vtbase + (size_t)vr1 * S_ + 128 + vc1);
  }
  __syncthreads();

  for (int t = 0; t < NT; ++t) {
    const int cur = t & 1;
    const int t0  = t * 128;
    const __bf16* ktb = &kt[cur][0];
    const __bf16* vtb = &vt[cur][0];

    // write staged tile t+1 into buf[cur^1] (race-free: barrier ended iter t-1)
    if (t + 1 < NT) {
      const int nxt = cur ^ 1;
      *(bf16x8*)(&kt[nxt][kr0 * LKT + kc0]) = rk0;
      *(bf16x8*)(&kt[nxt][kr1 * LKT + kc1]) = rk1;
      *(bf16x8*)(&vt[nxt][vr0 * LVT + vc0]) = rv0;
      *(bf16x8*)(&vt[nxt][vr1 * LVT + vc1]) = rv1;
    }
    // issue tile t+2 global loads (full-tile latency hiding)
    if (t + 2 < NT) {
      const int tn = t0 + 256;
      rk0 = *(const bf16x8*)(K + base + (size_t)(tn + kr0) * D_ + kc0);
      rk1 = *(const bf16x8*)(K + base + (size_t)(tn + kr1) * D_ + kc1);
      rv0 = *(const bf16x8*)(Vt + vtbase + (size_t)vr0 * S_ + tn + vc0);
      rv1 = *(const bf16x8*)(Vt + vtbase + (size_t)vr1 * S_ + tn + vc1);
    }

    // S^T tile: D[m=key][n=q]; lane (l15,quad): key = kti*16+quad*4+r, q = l15
    f32x4 sacc[8] = {};
    __builtin_amdgcn_s_setprio(1);
#pragma unroll
    for (int kti = 0; kti < 8; ++kti) {
      const __bf16* kr = ktb + (kti * 16 + l15) * LKT + quad * 8;
      const bf16x8 a0 = *(const bf16x8*)(kr);
      const bf16x8 a1 = *(const bf16x8*)(kr + 32);
      sacc[kti] = __builtin_amdgcn_mfma_f32_16x16x32_bf16(a0, qf[0], sacc[kti], 0, 0, 0);
      sacc[kti] = __builtin_amdgcn_mfma_f32_16x16x32_bf16(a1, qf[1], sacc[kti], 0, 0, 0);
    }
    __builtin_amdgcn_s_setprio(0);

    // scale (exp2 domain) + mask, running max with 4 independent chains
    f32x4 tm4;
#pragma unroll
    for (int r = 0; r < 4; ++r) tm4[r] = -1e30f;
#pragma unroll
    for (int kti = 0; kti < 8; ++kti) {
      const f32x4 mv = *(const f32x4*)(mfull + t0 + kti * 16 + quad * 4);
#pragma unroll
      for (int r = 0; r < 4; ++r) {
        sacc[kti][r] = sacc[kti][r] * SC + mv[r];
        tm4[r] = fmaxf(tm4[r], sacc[kti][r]);
      }
    }
    float tm = fmaxf(fmaxf(tm4[0], tm4[1]), fmaxf(tm4[2], tm4[3]));
    tm = fmaxf(tm, __shfl_xor(tm, 16));
    tm = fmaxf(tm, __shfl_xor(tm, 32));

    // defer-max (T13): only rescale when tile max grows past THR=8 (p <= 2^8)
    if (!__all(tm <= m_run + 8.f)) {
      const float mnew  = fmaxf(m_run, tm);
      const float alpha = __builtin_amdgcn_exp2f(m_run - mnew);
      m_run = mnew;
#pragma unroll
      for (int r = 0; r < 4; ++r) {
        const float aR = __shfl(alpha, quad * 4 + r);
        lacc[r] *= aR;
#pragma unroll
        for (int nt = 0; nt < 4; ++nt) oacc[nt][r] *= aR;
      }
    }

    // exp2 + pack + permlane-redistribute + PV + row-sum, per kb (32 keys each)
#pragma unroll
    for (int kb = 0; kb < 4; ++kb) {
      unsigned dd[2][2];
#pragma unroll
      for (int kk = 0; kk < 2; ++kk) {
        const int kti = 2 * kb + kk;
        float p[4];
#pragma unroll
        for (int r = 0; r < 4; ++r)
          p[r] = __builtin_amdgcn_exp2f(sacc[kti][r] - m_run);
        dd[kk][0] = cvt_pk_bf16(p[0], p[1]);
        dd[kk][1] = cvt_pk_bf16(p[2], p[3]);
      }
      // quad shuffle: rows [A0,A1,A2,A3],[B0,B1,B2,B3] -> [A0,A2,B0,B2],[A1,A3,B1,B3]
      unsigned a0 = dd[0][0], b0 = dd[1][0], a1 = dd[0][1], b1 = dd[1][1];
      asm("v_permlane32_swap_b32 %0, %1" : "+v"(a0), "+v"(b0));
      asm("v_permlane16_swap_b32 %0, %1" : "+v"(a0), "+v"(b0));
      asm("v_permlane32_swap_b32 %0, %1" : "+v"(a1), "+v"(b1));
      asm("v_permlane16_swap_b32 %0, %1" : "+v"(a1), "+v"(b1));
      union { unsigned u[4]; bf16x8 v; } pw;
      pw.u[0] = a0; pw.u[1] = a1; pw.u[2] = b0; pw.u[3] = b1;
      const bf16x8 pa = pw.v;  // A[q=l15][key = kb*32 + quad*8 + j]
      __builtin_amdgcn_s_setprio(1);
      lacc = __builtin_amdgcn_mfma_f32_16x16x32_bf16(pa, ones, lacc, 0, 0, 0);
#pragma unroll
      for (int nt = 0; nt < 4; ++nt) {
        const bf16x8 vf = *(const bf16x8*)(vtb + (nt * 16 + l15) * LVT + kb * 32 + quad * 8);
        oacc[nt] = __builtin_amdgcn_mfma_f32_16x16x32_bf16(pa, vf, oacc[nt], 0, 0, 0);
      }
      __builtin_amdgcn_s_setprio(0);
    }

    __syncthreads();  // single barrier: ds_writes visible + buf reuse guarded
  }

  // epilogue: divide by l (already in row layout via ones-MFMA), store ctx
#pragma unroll
  for (int r = 0; r < 4; ++r) {
    const float inv = 1.0f / lacc[r];
    const int row = qw + quad * 4 + r;
#pragma unroll
    for (int nt = 0; nt < 4; ++nt)
      O[base + (size_t)row * D_ + nt * 16 + l15] = (__bf16)(oacc[nt][r] * inv);
  }
}

extern "C" void kernel_launch(void* const* d_in, const int* in_sizes, int n_in,
                              void* d_out, int out_size, void* d_ws, size_t ws_size,
                              hipStream_t stream) {
  const float* x    = (const float*)d_in[0];
  const float* mask = (const float*)d_in[1];
  const float* Wq   = (const float*)d_in[2];
  const float* Wk   = (const float*)d_in[3];
  const float* Wv   = (const float*)d_in[4];
  const float* Wo   = (const float*)d_in[5];

  char* ws = (char*)d_ws;
  const size_t MB = 1ull << 20;
  const size_t NT = (size_t)B_ * S_ * D_;  // 4M elems, 8 MB bf16
  __bf16* xb  = (__bf16*)(ws);             // 8 MB; freed after qkv_gemm -> reused as cb
  __bf16* wqb = (__bf16*)(ws + 8 * MB);    // wq/wk/wv contiguous = packed [3072][1024]
  __bf16* wkb = (__bf16*)(ws + 10 * MB);
  __bf16* wvb = (__bf16*)(ws + 12 * MB);
  __bf16* wob = (__bf16*)(ws + 14 * MB);
  __bf16* qkv = (__bf16*)(ws + 16 * MB);   // 24 MB: Q, K, Vt
  __bf16* qb  = qkv;
  __bf16* kb  = qkv + NT;
  __bf16* vtb = qkv + 2 * NT;  // qkv_gemm sel==2 writes V pre-transposed here
  __bf16* cb  = xb;            // x consumed by qkv_gemm before attn writes ctx

  cvt_all<<<dim3(1024, 5), 256, 0, stream>>>(x, Wq, Wk, Wv, Wo, xb, wqb, wkb, wvb, wob);
  qkv_gemm<<<dim3(24, 32), 256, 0, stream>>>(xb, wqb, qkv);
  attn2<<<dim3(S_ / 128, H_, B_), 512, 0, stream>>>(qb, kb, vtb, mask, cb);
  o_gemm<<<dim3(8, 64), 256, 0, stream>>>(cb, wob, (float*)d_out);
}